// Round 1
// baseline (1322.534 us; speedup 1.0000x reference)
//
#include <hip/hip_runtime.h>
#include <hip/hip_bf16.h>
#include <cstdint>
#include <cstddef>

// Problem constants
#define Bx 64
#define Tt 512
#define Dd 2048
#define Hh 8
#define DR 512
#define Mm (Bx * Tt)      // 32768
#define Nn (Hh * DR)      // 4096
#define Kk Dd             // 2048

using half8 = __attribute__((ext_vector_type(8))) _Float16;
using half4v = __attribute__((ext_vector_type(4))) _Float16;
using f32x4 = __attribute__((ext_vector_type(4))) float;

__device__ __forceinline__ void gload_lds16(const void* gsrc, void* ldst) {
    __builtin_amdgcn_global_load_lds(
        (const __attribute__((address_space(1))) void*)gsrc,
        (__attribute__((address_space(3))) void*)ldst, 16, 0, 0);
}

__device__ __forceinline__ float fast_tanh(float x) {
    float ax = fabsf(x);
    float e = __expf(fminf(2.0f * ax, 20.0f));
    float t = (e - 1.0f) / (e + 1.0f);
    return copysignf(t, x);
}

// ---- convert x (fp32) -> fp16 ----
__global__ void cvt_x_kernel(const float4* __restrict__ x, half4v* __restrict__ xh, int n4) {
    int idx = blockIdx.x * blockDim.x + threadIdx.x;
    int stride = gridDim.x * blockDim.x;
    for (int i = idx; i < n4; i += stride) {
        float4 v = x[i];
        half4v hv;
        hv[0] = (_Float16)v.x; hv[1] = (_Float16)v.y;
        hv[2] = (_Float16)v.z; hv[3] = (_Float16)v.w;
        xh[i] = hv;
    }
}

// ---- convert W1 [H][D][DR] fp32 -> w1t [N=H*DR][K=D] fp16 (B^T layout) ----
__global__ void cvt_w1_kernel(const float* __restrict__ W1, _Float16* __restrict__ w1t) {
    __shared__ float tile[32][33];
    const int h = blockIdx.z;
    const int d0 = blockIdx.x * 32;
    const int r0 = blockIdx.y * 32;
    const int tr = threadIdx.x & 31;   // fast index
    const int td = threadIdx.x >> 5;   // 0..7
#pragma unroll
    for (int i = 0; i < 4; ++i) {
        int d = td + i * 8;
        tile[d][tr] = W1[((size_t)h * Dd + d0 + d) * DR + r0 + tr];
    }
    __syncthreads();
#pragma unroll
    for (int i = 0; i < 4; ++i) {
        int r = td + i * 8;
        w1t[((size_t)(h * DR + r0 + r)) * Kk + d0 + tr] = (_Float16)tile[tr][r];
    }
}

// ---- fused GEMM1 + tanh + (.@W2) partial-score reduction ----
// C tile 128x128, 4 waves (2x2), each wave 64x64 via 4x4 frags of 16x16x32 f16 MFMA.
__global__ __launch_bounds__(256) void gemm_fused_kernel(
    const _Float16* __restrict__ xh, const _Float16* __restrict__ w1t,
    const float* __restrict__ b1, const float* __restrict__ W2,
    float* __restrict__ scores)
{
    __shared__ _Float16 As[128 * 32];
    __shared__ _Float16 Bs[128 * 32];

    const int tid = threadIdx.x;
    const int lane = tid & 63;
    const int wid = tid >> 6;
    const int wm = wid >> 1, wn = wid & 1;
    const int g = lane >> 4, ln = lane & 15;
    const int m0 = blockIdx.x * 128;
    const int n0 = blockIdx.y * 128;

    f32x4 acc[4][4] = {};

    for (int kt = 0; kt < Kk; kt += 32) {
        // stage A and B tiles: 512 x 16B chunks each, 2 per thread per tile
#pragma unroll
        for (int it = 0; it < 2; ++it) {
            const int c = it * 256 + wid * 64 + lane;       // chunk id
            const int row = c >> 2;
            const int kp = c & 3;
            const int ldsbase = (it * 256 + wid * 64) * 8;  // halves (wave-uniform)
            gload_lds16(xh + (size_t)(m0 + row) * Kk + kt + kp * 8, As + ldsbase);
            gload_lds16(w1t + (size_t)(n0 + row) * Kk + kt + kp * 8, Bs + ldsbase);
        }
        __syncthreads();

        half8 a[4], b[4];
#pragma unroll
        for (int mi = 0; mi < 4; ++mi)
            a[mi] = *(const half8*)&As[(wm * 64 + mi * 16 + ln) * 32 + g * 8];
#pragma unroll
        for (int ni = 0; ni < 4; ++ni)
            b[ni] = *(const half8*)&Bs[(wn * 64 + ni * 16 + ln) * 32 + g * 8];
#pragma unroll
        for (int mi = 0; mi < 4; ++mi)
#pragma unroll
            for (int ni = 0; ni < 4; ++ni)
                acc[mi][ni] = __builtin_amdgcn_mfma_f32_16x16x32_f16(a[mi], b[ni], acc[mi][ni], 0, 0, 0);
        __syncthreads();
    }

    // Epilogue: h = tanh(acc + b1[n]); partial score = sum_n h * W2[n]
    const int h = n0 >> 9;  // head (BN=128 divides DR=512)
    float w2v[4], b1v[4];
#pragma unroll
    for (int ni = 0; ni < 4; ++ni) {
        int n = n0 + wn * 64 + ni * 16 + ln;   // global n == h*DR + r
        w2v[ni] = W2[n];
        b1v[ni] = b1[n];
    }

#pragma unroll
    for (int mi = 0; mi < 4; ++mi) {
#pragma unroll
        for (int r = 0; r < 4; ++r) {
            float p = 0.0f;
#pragma unroll
            for (int ni = 0; ni < 4; ++ni) {
                float v = acc[mi][ni][r] + b1v[ni];
                p += fast_tanh(v) * w2v[ni];
            }
            // reduce over the 16 lanes (cols) of this lane-group
            p += __shfl_xor(p, 8);
            p += __shfl_xor(p, 4);
            p += __shfl_xor(p, 2);
            p += __shfl_xor(p, 1);
            if (ln == 0) {
                int mg = m0 + wm * 64 + mi * 16 + g * 4 + r;
                int bb = mg >> 9;        // / T
                int t = mg & (Tt - 1);
                unsafeAtomicAdd(&scores[((size_t)bb * Hh + h) * Tt + t], p);
            }
        }
    }
}

// ---- softmax over T per (b,h) row ----
__global__ void softmax_kernel(const float* __restrict__ scores, float* __restrict__ attn) {
    const int bh = blockIdx.x;
    const int t = threadIdx.x;   // 512 threads
    __shared__ float red[8];
    float s = scores[(size_t)bh * Tt + t];
    float m = s;
#pragma unroll
    for (int mask = 32; mask >= 1; mask >>= 1) m = fmaxf(m, __shfl_xor(m, mask));
    if ((t & 63) == 0) red[t >> 6] = m;
    __syncthreads();
    float bm = red[0];
#pragma unroll
    for (int i = 1; i < 8; ++i) bm = fmaxf(bm, red[i]);
    float e = __expf(s - bm);
    float sum = e;
#pragma unroll
    for (int mask = 32; mask >= 1; mask >>= 1) sum += __shfl_xor(sum, mask);
    __syncthreads();
    if ((t & 63) == 0) red[t >> 6] = sum;
    __syncthreads();
    float tot = 0.0f;
#pragma unroll
    for (int i = 0; i < 8; ++i) tot += red[i];
    attn[(size_t)bh * Tt + t] = e / tot;
}

// ---- pooled[b,h,d] = sum_t attn[b,h,t] * x[b,t,d] ----
__global__ __launch_bounds__(256) void pool_kernel(
    const float* __restrict__ x, const float* __restrict__ attn, float* __restrict__ out)
{
    const int b = blockIdx.x;
    const int d = blockIdx.y * 256 + threadIdx.x;
    __shared__ float at[Tt * Hh];  // [t][h], 16KB
    for (int i = threadIdx.x; i < Tt * Hh; i += 256) {
        int hh = i >> 9;
        int t = i & (Tt - 1);
        at[t * Hh + hh] = attn[(size_t)b * (Hh * Tt) + i];
    }
    __syncthreads();

    float acc[Hh] = {};
    const float* xb = x + (size_t)b * Tt * Dd + d;
#pragma unroll 4
    for (int t = 0; t < Tt; ++t) {
        float xv = xb[(size_t)t * Dd];
        const float4 a0 = *(const float4*)&at[t * Hh];
        const float4 a1 = *(const float4*)&at[t * Hh + 4];
        acc[0] = fmaf(a0.x, xv, acc[0]);
        acc[1] = fmaf(a0.y, xv, acc[1]);
        acc[2] = fmaf(a0.z, xv, acc[2]);
        acc[3] = fmaf(a0.w, xv, acc[3]);
        acc[4] = fmaf(a1.x, xv, acc[4]);
        acc[5] = fmaf(a1.y, xv, acc[5]);
        acc[6] = fmaf(a1.z, xv, acc[6]);
        acc[7] = fmaf(a1.w, xv, acc[7]);
    }
#pragma unroll
    for (int hh = 0; hh < Hh; ++hh)
        out[(size_t)b * (Hh * Dd) + (size_t)hh * Dd + d] = acc[hh];
}

extern "C" void kernel_launch(void* const* d_in, const int* in_sizes, int n_in,
                              void* d_out, int out_size, void* d_ws, size_t ws_size,
                              hipStream_t stream) {
    const float* x  = (const float*)d_in[0];
    const float* W1 = (const float*)d_in[1];
    const float* b1 = (const float*)d_in[2];
    const float* W2 = (const float*)d_in[3];
    float* out = (float*)d_out;

    char* ws = (char*)d_ws;
    const size_t xh_bytes  = (size_t)Mm * Kk * sizeof(_Float16);   // 134,217,728
    const size_t w1t_bytes = (size_t)Nn * Kk * sizeof(_Float16);   // 16,777,216
    const size_t sc_bytes  = (size_t)Bx * Hh * Tt * sizeof(float); // 1,048,576
    _Float16* xh   = (_Float16*)ws;
    _Float16* w1t  = (_Float16*)(ws + xh_bytes);
    float* scores  = (float*)(ws + xh_bytes + w1t_bytes);
    float* attn    = (float*)(ws + xh_bytes + w1t_bytes + sc_bytes);

    hipMemsetAsync(scores, 0, sc_bytes, stream);
    cvt_x_kernel<<<2048, 256, 0, stream>>>((const float4*)x, (half4v*)xh, (Mm * Kk) / 4);
    cvt_w1_kernel<<<dim3(Dd / 32, DR / 32, Hh), 256, 0, stream>>>(W1, w1t);
    gemm_fused_kernel<<<dim3(Mm / 128, Nn / 128), 256, 0, stream>>>(xh, w1t, b1, W2, scores);
    softmax_kernel<<<Bx * Hh, Tt, 0, stream>>>(scores, attn);
    pool_kernel<<<dim3(Bx, Dd / 256), 256, 0, stream>>>(x, attn, out);
}

// Round 3
// 986.532 us; speedup vs baseline: 1.3406x; 1.3406x over previous
//
#include <hip/hip_runtime.h>
#include <hip/hip_bf16.h>
#include <cstdint>
#include <cstddef>

// Problem constants
#define Bx 64
#define Tt 512
#define Dd 2048
#define Hh 8
#define DR 512
#define Mm (Bx * Tt)      // 32768
#define Nn (Hh * DR)      // 4096
#define Kk Dd             // 2048

// GEMM tile params (256^2 8-phase template)
#define BM 256
#define BN 256
#define BK 64
#define NT (Kk / BK)      // 32 K-tiles

using half8 = __attribute__((ext_vector_type(8))) _Float16;
using half4v = __attribute__((ext_vector_type(4))) _Float16;
using f32x4 = __attribute__((ext_vector_type(4))) float;

__device__ __forceinline__ void gload_lds16(const void* gsrc, void* ldst) {
    __builtin_amdgcn_global_load_lds(
        (const __attribute__((address_space(1))) void*)gsrc,
        (__attribute__((address_space(3))) void*)ldst, 16, 0, 0);
}

__device__ __forceinline__ float fast_tanh(float x) {
    float ax = fabsf(x);
    float e = __expf(fminf(2.0f * ax, 20.0f));
    float t = (e - 1.0f) / (e + 1.0f);
    return copysignf(t, x);
}

// ---- convert x (fp32) -> fp16 ----
__global__ void cvt_x_kernel(const float4* __restrict__ x, half4v* __restrict__ xh, int n4) {
    int idx = blockIdx.x * blockDim.x + threadIdx.x;
    int stride = gridDim.x * blockDim.x;
    for (int i = idx; i < n4; i += stride) {
        float4 v = x[i];
        half4v hv;
        hv[0] = (_Float16)v.x; hv[1] = (_Float16)v.y;
        hv[2] = (_Float16)v.z; hv[3] = (_Float16)v.w;
        xh[i] = hv;
    }
}

// ---- convert W1 [H][D][DR] fp32 -> w1t [N=H*DR][K=D] fp16 (B^T layout) ----
__global__ void cvt_w1_kernel(const float* __restrict__ W1, _Float16* __restrict__ w1t) {
    __shared__ float tile[32][33];
    const int h = blockIdx.z;
    const int d0 = blockIdx.x * 32;
    const int r0 = blockIdx.y * 32;
    const int tr = threadIdx.x & 31;
    const int td = threadIdx.x >> 5;
#pragma unroll
    for (int i = 0; i < 4; ++i) {
        int d = td + i * 8;
        tile[d][tr] = W1[((size_t)h * Dd + d0 + d) * DR + r0 + tr];
    }
    __syncthreads();
#pragma unroll
    for (int i = 0; i < 4; ++i) {
        int r = td + i * 8;
        w1t[((size_t)(h * DR + r0 + r)) * Kk + d0 + tr] = (_Float16)tile[tr][r];
    }
}

// LDS half-buffer map (bytes): buf b in [0,2): base b*65536
//   A-half0 +0, A-half1 +16384, B-half0 +32768, B-half1 +49152
// Swizzle: logical byte p of row-major [128 rows][128 B] stored at col ^ ((row&7)<<4).
// global_load_lds writes linearly (dest = wave base + lane*16), so the SOURCE
// address carries the inverse (= same, involution) swizzle; reads apply the XOR.

#define STAGE_HALF(gptr, grow0, kt, ldsoff)                                               \
  {                                                                                       \
    _Pragma("unroll")                                                                     \
    for (int r_ = 0; r_ < 2; ++r_) {                                                      \
      const int o_ = r_ * 8192 + tid * 16;                                                \
      const int lrow_ = o_ >> 7;                                                          \
      const int qcb_ = (o_ & 127) ^ ((lrow_ & 7) << 4);                                   \
      const _Float16* src_ = (gptr) + (size_t)((grow0) + lrow_) * Kk + (kt) + (qcb_ >> 1);\
      gload_lds16(src_, lds + (ldsoff) + r_ * 8192 + wid * 1024);                         \
    }                                                                                     \
  }

#define READ_A(quad)                                                                      \
  {                                                                                       \
    _Pragma("unroll")                                                                     \
    for (int mq_ = 0; mq_ < 4; ++mq_) {                                                   \
      _Pragma("unroll")                                                                   \
      for (int s_ = 0; s_ < 2; ++s_) {                                                    \
        const int row_ = (quad) * 64 + mq_ * 16 + ln;                                     \
        a[mq_][s_] = *(const half8*)(Ab + ((row_ << 7) +                                  \
                        ((s_ * 64 + g * 16) ^ ((row_ & 7) << 4))));                       \
      }                                                                                   \
    }                                                                                     \
  }

#define READ_B2(pair)                                                                     \
  {                                                                                       \
    _Pragma("unroll")                                                                     \
    for (int nq_ = 0; nq_ < 2; ++nq_) {                                                   \
      _Pragma("unroll")                                                                   \
      for (int s_ = 0; s_ < 2; ++s_) {                                                    \
        const int row_ = brow + ((pair) * 2 + nq_) * 16 + ln;                             \
        b[(pair) * 2 + nq_][s_] = *(const half8*)(Bb + ((row_ << 7) +                     \
                        ((s_ * 64 + g * 16) ^ ((row_ & 7) << 4))));                       \
      }                                                                                   \
    }                                                                                     \
  }

#define MMA(qm, qn)                                                                       \
  {                                                                                       \
    __builtin_amdgcn_s_setprio(1);                                                        \
    _Pragma("unroll")                                                                     \
    for (int mq_ = 0; mq_ < 4; ++mq_) {                                                   \
      _Pragma("unroll")                                                                   \
      for (int nq_ = 0; nq_ < 2; ++nq_) {                                                 \
        _Pragma("unroll")                                                                 \
        for (int s_ = 0; s_ < 2; ++s_)                                                    \
          acc[(qm) * 4 + mq_][(qn) * 2 + nq_] = __builtin_amdgcn_mfma_f32_16x16x32_f16(   \
              a[mq_][s_], b[(qn) * 2 + nq_][s_], acc[(qm) * 4 + mq_][(qn) * 2 + nq_],     \
              0, 0, 0);                                                                   \
      }                                                                                   \
    }                                                                                     \
    __builtin_amdgcn_s_setprio(0);                                                        \
  }

// ---- fused GEMM1 (256x256x64, 8-wave, 8-phase) + tanh + (.@W2) score reduction ----
// Race-safety invariant: each LDS region is staged only in a phase strictly after
// the phase holding its last ds_read, with a post-MMA barrier in between:
//   A-halves of tile t: last read ph2(t)  -> staged for t+1 in ph0/ph1 of t (other buf)
//   B-halves of tile t: last read ph1(t)  -> staged for t+2 in ph2/ph3 of t (same buf)
// Read-after-write covered by the per-tile counted vmcnt(4) at ph3.
__global__ __launch_bounds__(512, 2) void gemm_fused_kernel(
    const _Float16* __restrict__ xh, const _Float16* __restrict__ w1t,
    const float* __restrict__ b1, const float* __restrict__ W2,
    float* __restrict__ scores)
{
    extern __shared__ char lds[];  // 131072 bytes

    const int tid = threadIdx.x;
    const int lane = tid & 63;
    const int wid = tid >> 6;          // 0..7
    const int wr = wid >> 2;           // 0..1  (M)
    const int wc = wid & 3;            // 0..3  (N)
    const int g = lane >> 4, ln = lane & 15;

    // T1: bijective XCD swizzle (2048 % 8 == 0), A-reuse orientation:
    // each XCD's consecutive blocks share bx (A-tile L2-resident); B streams from L3.
    const int bid = blockIdx.x;
    const int sbid = (bid & 7) * 256 + (bid >> 3);
    const int bx = sbid >> 4;          // 0..127 (M)
    const int by = sbid & 15;          // 0..15  (N)
    const int m0 = bx * BM;
    const int n0 = by * BN;

    f32x4 acc[8][4] = {};
    half8 a[4][2], b[4][2];

    // Prologue: tile0 all 4 halves + B0[1],B1[1]  (A[1] staged in ph0/ph1 of t=0)
    STAGE_HALF(xh,  m0,        0,  0);
    STAGE_HALF(xh,  m0 + 128,  0,  16384);
    STAGE_HALF(w1t, n0,        0,  32768);
    STAGE_HALF(w1t, n0 + 128,  0,  49152);
    STAGE_HALF(w1t, n0,        BK, 65536 + 32768);
    STAGE_HALF(w1t, n0 + 128,  BK, 65536 + 49152);
    asm volatile("s_waitcnt vmcnt(4)" ::: "memory");  // tile0 (oldest 8) landed
    __builtin_amdgcn_s_barrier();

    for (int t = 0; t < NT; ++t) {
        const int buf = t & 1;
        const int bufn = buf ^ 1;
        char* Ab = lds + buf * 65536 + wr * 16384;
        char* Bb = lds + buf * 65536 + 32768 + (wc >> 1) * 16384;
        const int brow = (wc & 1) * 64;

        // phase 0: read A quad0 + B pair0; stage A0[t+1] (other buf)
        READ_A(0);
        READ_B2(0);
        if (t + 1 < NT) STAGE_HALF(xh, m0, (t + 1) * BK, bufn * 65536 + 0);
        __builtin_amdgcn_s_barrier();
        MMA(0, 0);
        __builtin_amdgcn_s_barrier();

        // phase 1: read B pair1; stage A1[t+1] (other buf)
        READ_B2(1);
        if (t + 1 < NT) STAGE_HALF(xh, m0 + 128, (t + 1) * BK, bufn * 65536 + 16384);
        __builtin_amdgcn_s_barrier();
        MMA(0, 1);
        __builtin_amdgcn_s_barrier();

        // phase 2: read A quad1; stage B0[t+2] (same buf — B reads done by ph1 barrier)
        READ_A(1);
        if (t + 2 < NT) STAGE_HALF(w1t, n0, (t + 2) * BK, buf * 65536 + 32768);
        __builtin_amdgcn_s_barrier();
        MMA(1, 0);
        __builtin_amdgcn_s_barrier();

        // phase 3: stage B1[t+2]; per-tile counted vmcnt; MFMA
        if (t + 2 < NT) STAGE_HALF(w1t, n0 + 128, (t + 2) * BK, buf * 65536 + 49152);
        if (t < NT - 2)       asm volatile("s_waitcnt vmcnt(4)" ::: "memory");
        else if (t == NT - 2) asm volatile("s_waitcnt vmcnt(0)" ::: "memory");
        __builtin_amdgcn_s_barrier();
        MMA(1, 1);
        __builtin_amdgcn_s_barrier();
    }

    // Epilogue: h = tanh(acc + b1[n]); partial score = sum_n h * W2[n]
    const int h = n0 >> 9;  // whole 256-col block lies in one head (256 | 512)
    float w2v[4], b1v[4];
#pragma unroll
    for (int ni = 0; ni < 4; ++ni) {
        int n = n0 + wc * 64 + ni * 16 + ln;
        w2v[ni] = W2[n];
        b1v[ni] = b1[n];
    }

#pragma unroll
    for (int mi = 0; mi < 8; ++mi) {
#pragma unroll
        for (int r = 0; r < 4; ++r) {
            float p = 0.0f;
#pragma unroll
            for (int ni = 0; ni < 4; ++ni) {
                float v = acc[mi][ni][r] + b1v[ni];
                p += fast_tanh(v) * w2v[ni];
            }
            p += __shfl_xor(p, 8);
            p += __shfl_xor(p, 4);
            p += __shfl_xor(p, 2);
            p += __shfl_xor(p, 1);
            if (ln == 0) {
                int mg = m0 + wr * 128 + mi * 16 + g * 4 + r;
                int bb = mg >> 9;
                int tt = mg & (Tt - 1);
                unsafeAtomicAdd(&scores[((size_t)bb * Hh + h) * Tt + tt], p);
            }
        }
    }
}

// ---- softmax over T per (b,h) row ----
__global__ void softmax_kernel(const float* __restrict__ scores, float* __restrict__ attn) {
    const int bh = blockIdx.x;
    const int t = threadIdx.x;   // 512 threads
    __shared__ float red[8];
    float s = scores[(size_t)bh * Tt + t];
    float m = s;
#pragma unroll
    for (int mask = 32; mask >= 1; mask >>= 1) m = fmaxf(m, __shfl_xor(m, mask));
    if ((t & 63) == 0) red[t >> 6] = m;
    __syncthreads();
    float bm = red[0];
#pragma unroll
    for (int i = 1; i < 8; ++i) bm = fmaxf(bm, red[i]);
    float e = __expf(s - bm);
    float sum = e;
#pragma unroll
    for (int mask = 32; mask >= 1; mask >>= 1) sum += __shfl_xor(sum, mask);
    __syncthreads();
    if ((t & 63) == 0) red[t >> 6] = sum;
    __syncthreads();
    float tot = 0.0f;
#pragma unroll
    for (int i = 0; i < 8; ++i) tot += red[i];
    attn[(size_t)bh * Tt + t] = e / tot;
}

// ---- pooled[b,h,d] = sum_t attn[b,h,t] * x[b,t,d]  (reads fp16 xh) ----
__global__ __launch_bounds__(256) void pool_kernel(
    const _Float16* __restrict__ xh, const float* __restrict__ attn, float* __restrict__ out)
{
    const int b = blockIdx.x;
    const int d = blockIdx.y * 256 + threadIdx.x;
    __shared__ float at[Tt * Hh];  // [t][h], 16KB
    for (int i = threadIdx.x; i < Tt * Hh; i += 256) {
        int hh = i >> 9;
        int t = i & (Tt - 1);
        at[t * Hh + hh] = attn[(size_t)b * (Hh * Tt) + i];
    }
    __syncthreads();

    float acc[Hh] = {};
    const _Float16* xb = xh + (size_t)b * Tt * Dd + d;
#pragma unroll 4
    for (int t = 0; t < Tt; ++t) {
        float xv = (float)xb[(size_t)t * Dd];
        const float4 a0 = *(const float4*)&at[t * Hh];
        const float4 a1 = *(const float4*)&at[t * Hh + 4];
        acc[0] = fmaf(a0.x, xv, acc[0]);
        acc[1] = fmaf(a0.y, xv, acc[1]);
        acc[2] = fmaf(a0.z, xv, acc[2]);
        acc[3] = fmaf(a0.w, xv, acc[3]);
        acc[4] = fmaf(a1.x, xv, acc[4]);
        acc[5] = fmaf(a1.y, xv, acc[5]);
        acc[6] = fmaf(a1.z, xv, acc[6]);
        acc[7] = fmaf(a1.w, xv, acc[7]);
    }
#pragma unroll
    for (int hh = 0; hh < Hh; ++hh)
        out[(size_t)b * (Hh * Dd) + (size_t)hh * Dd + d] = acc[hh];
}

extern "C" void kernel_launch(void* const* d_in, const int* in_sizes, int n_in,
                              void* d_out, int out_size, void* d_ws, size_t ws_size,
                              hipStream_t stream) {
    const float* x  = (const float*)d_in[0];
    const float* W1 = (const float*)d_in[1];
    const float* b1 = (const float*)d_in[2];
    const float* W2 = (const float*)d_in[3];
    float* out = (float*)d_out;

    char* ws = (char*)d_ws;
    const size_t xh_bytes  = (size_t)Mm * Kk * sizeof(_Float16);   // 134 MB
    const size_t w1t_bytes = (size_t)Nn * Kk * sizeof(_Float16);   // 16 MB
    const size_t sc_bytes  = (size_t)Bx * Hh * Tt * sizeof(float); // 1 MB
    _Float16* xh   = (_Float16*)ws;
    _Float16* w1t  = (_Float16*)(ws + xh_bytes);
    float* scores  = (float*)(ws + xh_bytes + w1t_bytes);
    float* attn    = (float*)(ws + xh_bytes + w1t_bytes + sc_bytes);

    // Allow 128 KiB dynamic LDS (host-side attribute; not a stream op).
    hipFuncSetAttribute((const void*)gemm_fused_kernel,
                        hipFuncAttributeMaxDynamicSharedMemorySize, 131072);

    hipMemsetAsync(scores, 0, sc_bytes, stream);
    cvt_x_kernel<<<2048, 256, 0, stream>>>((const float4*)x, (half4v*)xh, (Mm * Kk) / 4);
    cvt_w1_kernel<<<dim3(Dd / 32, DR / 32, Hh), 256, 0, stream>>>(W1, w1t);
    gemm_fused_kernel<<<dim3((Mm / BM) * (Nn / BN)), 512, 131072, stream>>>(xh, w1t, b1, W2, scores);
    softmax_kernel<<<Bx * Hh, Tt, 0, stream>>>(scores, attn);
    pool_kernel<<<dim3(Bx, Dd / 256), 256, 0, stream>>>(xh, attn, out);
}

// Round 5
// 974.319 us; speedup vs baseline: 1.3574x; 1.0125x over previous
//
#include <hip/hip_runtime.h>
#include <hip/hip_bf16.h>
#include <cstdint>
#include <cstddef>

// Problem constants
#define Bx 64
#define Tt 512
#define Dd 2048
#define Hh 8
#define DR 512
#define Mm (Bx * Tt)      // 32768
#define Nn (Hh * DR)      // 4096
#define Kk Dd             // 2048

// GEMM tile params (256^2 8-phase template)
#define BM 256
#define BN 256
#define BK 64
#define NT (Kk / BK)      // 32 K-tiles

using half8 = __attribute__((ext_vector_type(8))) _Float16;
using f32x4 = __attribute__((ext_vector_type(4))) float;

__device__ __forceinline__ void gload_lds16(const void* gsrc, void* ldst) {
    __builtin_amdgcn_global_load_lds(
        (const __attribute__((address_space(1))) void*)gsrc,
        (__attribute__((address_space(3))) void*)ldst, 16, 0, 0);
}

__device__ __forceinline__ float fast_tanh(float x) {
    float ax = fabsf(x);
    float e = __expf(fminf(2.0f * ax, 20.0f));
    float t = (e - 1.0f) / (e + 1.0f);
    return copysignf(t, x);
}

// ---- convert x (fp32) -> fp16, half8 (16B) stores ----
__global__ void cvt_x_kernel(const float4* __restrict__ x, half8* __restrict__ xh, int n8) {
    int idx = blockIdx.x * blockDim.x + threadIdx.x;
    int stride = gridDim.x * blockDim.x;
    for (int i = idx; i < n8; i += stride) {
        float4 v0 = x[2 * i];
        float4 v1 = x[2 * i + 1];
        half8 h;
        h[0] = (_Float16)v0.x; h[1] = (_Float16)v0.y;
        h[2] = (_Float16)v0.z; h[3] = (_Float16)v0.w;
        h[4] = (_Float16)v1.x; h[5] = (_Float16)v1.y;
        h[6] = (_Float16)v1.z; h[7] = (_Float16)v1.w;
        xh[i] = h;
    }
}

// ---- convert W1 [H][D][DR] fp32 -> w1t [N=H*DR][K=D] fp16 (B^T layout) ----
__global__ void cvt_w1_kernel(const float* __restrict__ W1, _Float16* __restrict__ w1t) {
    __shared__ float tile[32][33];
    const int h = blockIdx.z;
    const int d0 = blockIdx.x * 32;
    const int r0 = blockIdx.y * 32;
    const int tr = threadIdx.x & 31;
    const int td = threadIdx.x >> 5;
#pragma unroll
    for (int i = 0; i < 4; ++i) {
        int d = td + i * 8;
        tile[d][tr] = W1[((size_t)h * Dd + d0 + d) * DR + r0 + tr];
    }
    __syncthreads();
#pragma unroll
    for (int i = 0; i < 4; ++i) {
        int r = td + i * 8;
        w1t[((size_t)(h * DR + r0 + r)) * Kk + d0 + tr] = (_Float16)tile[tr][r];
    }
}

// LDS half-buffer map (bytes): buf b in [0,2): base b*65536
//   A-half0 +0, A-half1 +16384, B-half0 +32768, B-half1 +49152
// Swizzle: logical byte p of row-major [128 rows][128 B] stored at col ^ ((row&7)<<4).
// global_load_lds writes linearly; the SOURCE address carries the involution;
// ds_reads apply the same XOR (both-sides rule).

// Stage one 128x64 half-tile from persistent per-thread pointer p (2 x 16B/thread).
#define G2(p, ldsoff)                                                      \
  {                                                                        \
    gload_lds16((p), lds + (ldsoff) + ldst);                               \
    gload_lds16((p) + (size_t)64 * Kk, lds + (ldsoff) + 8192 + ldst);      \
  }

#define RD_A(quad)                                                         \
  {                                                                        \
    _Pragma("unroll")                                                      \
    for (int mq_ = 0; mq_ < 4; ++mq_) {                                    \
      a[mq_][0] = *(const half8*)(lds + (aOff0 + ((quad) * 8192 + mq_ * 2048))); \
      a[mq_][1] = *(const half8*)(lds + (aOff1 + ((quad) * 8192 + mq_ * 2048))); \
    }                                                                      \
  }

#define RD_B(pair)                                                         \
  {                                                                        \
    _Pragma("unroll")                                                      \
    for (int nq_ = 0; nq_ < 2; ++nq_) {                                    \
      const int j_ = (pair) * 2 + nq_;                                     \
      b[j_][0] = *(const half8*)(lds + (bOff0 + j_ * 2048));               \
      b[j_][1] = *(const half8*)(lds + (bOff1 + j_ * 2048));               \
    }                                                                      \
  }

#define MMA(qm, qn)                                                                       \
  {                                                                                       \
    __builtin_amdgcn_s_setprio(1);                                                        \
    _Pragma("unroll")                                                                     \
    for (int mq_ = 0; mq_ < 4; ++mq_) {                                                   \
      _Pragma("unroll")                                                                   \
      for (int nq_ = 0; nq_ < 2; ++nq_) {                                                 \
        _Pragma("unroll")                                                                 \
        for (int s_ = 0; s_ < 2; ++s_)                                                    \
          acc[(qm) * 4 + mq_][(qn) * 2 + nq_] = __builtin_amdgcn_mfma_f32_16x16x32_f16(   \
              a[mq_][s_], b[(qn) * 2 + nq_][s_], acc[(qm) * 4 + mq_][(qn) * 2 + nq_],     \
              0, 0, 0);                                                                   \
      }                                                                                   \
    }                                                                                     \
    __builtin_amdgcn_s_setprio(0);                                                        \
  }

// ---- fused GEMM1 (256x256x64, 8-wave, 8-phase) + tanh + (.@W2) score reduction ----
// Race-safety invariant (unchanged from verified round-3 schedule):
//   A-halves of tile t: last read ph2(t)  -> staged for t+1 in ph0/ph1 of t (other buf)
//   B-halves of tile t: last read ph1(t)  -> staged for t+2 in ph2/ph3 of t (same buf)
// Read-after-write covered by the per-tile counted vmcnt(4) at ph3.
__global__ __launch_bounds__(512, 2) void gemm_fused_kernel(
    const _Float16* __restrict__ xh, const _Float16* __restrict__ w1t,
    const float* __restrict__ b1, const float* __restrict__ W2,
    float* __restrict__ scores)
{
    extern __shared__ char lds[];  // 131072 bytes

    const int tid = threadIdx.x;
    const int lane = tid & 63;
    const int wid = tid >> 6;          // 0..7
    const int wr = wid >> 2;           // 0..1  (M)
    const int wc = wid & 3;            // 0..3  (N)
    const int g = lane >> 4, ln = lane & 15;

    // T1: bijective XCD swizzle (2048 % 8 == 0), A-reuse orientation.
    const int bid = blockIdx.x;
    const int sbid = (bid & 7) * 256 + (bid >> 3);
    const int bx = sbid >> 4;          // 0..127 (M)
    const int by = sbid & 15;          // 0..15  (N)
    const int m0 = bx * BM;
    const int n0 = by * BN;

    f32x4 acc[8][4] = {};
    half8 a[4][2], b[4][2];

    // ---- hoisted per-lane LDS read byte-offsets (buf0 state) ----
    const int xmask = (ln & 7) << 4;
    int aOff0 = wr * 16384 + ln * 128 + ((g * 16) ^ xmask);
    int aOff1 = wr * 16384 + ln * 128 + ((64 + g * 16) ^ xmask);
    int bOff0 = 32768 + (wc >> 1) * 16384 + ((wc & 1) * 64 + ln) * 128 + ((g * 16) ^ xmask);
    int bOff1 = 32768 + (wc >> 1) * 16384 + ((wc & 1) * 64 + ln) * 128 + ((64 + g * 16) ^ xmask);

    // ---- hoisted per-thread global stage pointers ----
    const int srow = tid >> 3;                                           // 0..63
    const int sqc = ((((tid & 7) * 16) ^ (((tid >> 3) & 7) << 4)) >> 1); // halves
    const _Float16* pA0 = xh + (size_t)(m0 + srow) * Kk + sqc;
    const _Float16* pA1 = pA0 + (size_t)128 * Kk;
    const _Float16* pB0 = w1t + (size_t)(n0 + srow) * Kk + sqc;
    const _Float16* pB1 = pB0 + (size_t)128 * Kk;
    const int ldst = wid * 1024;       // wave-uniform LDS lane-block offset

    // Prologue: tile0 all 4 halves @buf0 + B0[1],B1[1] @buf1
    G2(pA0, 0);
    G2(pA1, 16384);
    G2(pB0, 32768);
    G2(pB1, 49152);
    pB0 += BK; pB1 += BK;
    G2(pB0, 65536 + 32768);
    G2(pB1, 65536 + 49152);
    pB0 += BK; pB1 += BK;              // now point at tile 2
    pA0 += BK; pA1 += BK;              // now point at tile 1
    asm volatile("s_waitcnt vmcnt(4)" ::: "memory");  // tile0 (oldest 8) landed
    __builtin_amdgcn_s_barrier();

    for (int t = 0; t < NT; ++t) {
        const int buf = t & 1;
        const int bufn = buf ^ 1;
        const int stA = bufn * 65536;  // A[t+1] goes to other buffer
        const int stB = buf * 65536;   // B[t+2] goes to same buffer

        // phase 0: read A quad0 + B pair0; stage A0[t+1]
        RD_A(0);
        RD_B(0);
        if (t + 1 < NT) G2(pA0, stA + 0);
        pA0 += BK;
        __builtin_amdgcn_s_barrier();
        MMA(0, 0);
        __builtin_amdgcn_s_barrier();

        // phase 1: read B pair1; stage A1[t+1]
        RD_B(1);
        if (t + 1 < NT) G2(pA1, stA + 16384);
        pA1 += BK;
        __builtin_amdgcn_s_barrier();
        MMA(0, 1);
        __builtin_amdgcn_s_barrier();

        // phase 2: read A quad1; stage B0[t+2] (B reads of tile t done by ph1 barrier)
        RD_A(1);
        if (t + 2 < NT) G2(pB0, stB + 32768);
        pB0 += BK;
        __builtin_amdgcn_s_barrier();
        MMA(1, 0);
        __builtin_amdgcn_s_barrier();

        // phase 3: stage B1[t+2]; per-tile counted vmcnt; MFMA
        if (t + 2 < NT) G2(pB1, stB + 49152);
        pB1 += BK;
        if (t < NT - 2)       asm volatile("s_waitcnt vmcnt(4)" ::: "memory");
        else if (t == NT - 2) asm volatile("s_waitcnt vmcnt(0)" ::: "memory");
        __builtin_amdgcn_s_barrier();
        MMA(1, 1);
        __builtin_amdgcn_s_barrier();

        // buffer toggle for LDS read offsets
        aOff0 ^= 65536; aOff1 ^= 65536; bOff0 ^= 65536; bOff1 ^= 65536;
    }

    // Epilogue: h = tanh(acc + b1[n]); partial score = sum_n h * W2[n]
    const int h = n0 >> 9;  // whole 256-col block lies in one head
    float w2v[4], b1v[4];
#pragma unroll
    for (int ni = 0; ni < 4; ++ni) {
        int n = n0 + wc * 64 + ni * 16 + ln;
        w2v[ni] = W2[n];
        b1v[ni] = b1[n];
    }

#pragma unroll
    for (int mi = 0; mi < 8; ++mi) {
#pragma unroll
        for (int r = 0; r < 4; ++r) {
            float p = 0.0f;
#pragma unroll
            for (int ni = 0; ni < 4; ++ni) {
                float v = acc[mi][ni][r] + b1v[ni];
                p += fast_tanh(v) * w2v[ni];
            }
            p += __shfl_xor(p, 8);
            p += __shfl_xor(p, 4);
            p += __shfl_xor(p, 2);
            p += __shfl_xor(p, 1);
            if (ln == 0) {
                int mg = m0 + wr * 128 + mi * 16 + g * 4 + r;
                int bb = mg >> 9;
                int tt = mg & (Tt - 1);
                unsafeAtomicAdd(&scores[((size_t)bb * Hh + h) * Tt + tt], p);
            }
        }
    }
}

// ---- softmax over T per (b,h) row ----
__global__ void softmax_kernel(const float* __restrict__ scores, float* __restrict__ attn) {
    const int bh = blockIdx.x;
    const int t = threadIdx.x;   // 512 threads
    __shared__ float red[8];
    float s = scores[(size_t)bh * Tt + t];
    float m = s;
#pragma unroll
    for (int mask = 32; mask >= 1; mask >>= 1) m = fmaxf(m, __shfl_xor(m, mask));
    if ((t & 63) == 0) red[t >> 6] = m;
    __syncthreads();
    float bm = red[0];
#pragma unroll
    for (int i = 1; i < 8; ++i) bm = fmaxf(bm, red[i]);
    float e = __expf(s - bm);
    float sum = e;
#pragma unroll
    for (int mask = 32; mask >= 1; mask >>= 1) sum += __shfl_xor(sum, mask);
    __syncthreads();
    if ((t & 63) == 0) red[t >> 6] = sum;
    __syncthreads();
    float tot = 0.0f;
#pragma unroll
    for (int i = 0; i < 8; ++i) tot += red[i];
    attn[(size_t)bh * Tt + t] = e / tot;
}

// ---- pooled[b,h,d] = sum_t attn[b,h,t] * x[b,t,d]  (reads fp16 xh) ----
__global__ __launch_bounds__(256) void pool_kernel(
    const _Float16* __restrict__ xh, const float* __restrict__ attn, float* __restrict__ out)
{
    const int b = blockIdx.x;
    const int d = blockIdx.y * 256 + threadIdx.x;
    __shared__ float at[Tt * Hh];  // [t][h], 16KB
    for (int i = threadIdx.x; i < Tt * Hh; i += 256) {
        int hh = i >> 9;
        int t = i & (Tt - 1);
        at[t * Hh + hh] = attn[(size_t)b * (Hh * Tt) + i];
    }
    __syncthreads();

    float acc[Hh] = {};
    const _Float16* xb = xh + (size_t)b * Tt * Dd + d;
#pragma unroll 4
    for (int t = 0; t < Tt; ++t) {
        float xv = (float)xb[(size_t)t * Dd];
        const float4 a0 = *(const float4*)&at[t * Hh];
        const float4 a1 = *(const float4*)&at[t * Hh + 4];
        acc[0] = fmaf(a0.x, xv, acc[0]);
        acc[1] = fmaf(a0.y, xv, acc[1]);
        acc[2] = fmaf(a0.z, xv, acc[2]);
        acc[3] = fmaf(a0.w, xv, acc[3]);
        acc[4] = fmaf(a1.x, xv, acc[4]);
        acc[5] = fmaf(a1.y, xv, acc[5]);
        acc[6] = fmaf(a1.z, xv, acc[6]);
        acc[7] = fmaf(a1.w, xv, acc[7]);
    }
#pragma unroll
    for (int hh = 0; hh < Hh; ++hh)
        out[(size_t)b * (Hh * Dd) + (size_t)hh * Dd + d] = acc[hh];
}

extern "C" void kernel_launch(void* const* d_in, const int* in_sizes, int n_in,
                              void* d_out, int out_size, void* d_ws, size_t ws_size,
                              hipStream_t stream) {
    const float* x  = (const float*)d_in[0];
    const float* W1 = (const float*)d_in[1];
    const float* b1 = (const float*)d_in[2];
    const float* W2 = (const float*)d_in[3];
    float* out = (float*)d_out;

    char* ws = (char*)d_ws;
    const size_t xh_bytes  = (size_t)Mm * Kk * sizeof(_Float16);   // 134 MB
    const size_t w1t_bytes = (size_t)Nn * Kk * sizeof(_Float16);   // 16 MB
    const size_t sc_bytes  = (size_t)Bx * Hh * Tt * sizeof(float); // 1 MB
    _Float16* xh   = (_Float16*)ws;
    _Float16* w1t  = (_Float16*)(ws + xh_bytes);
    float* scores  = (float*)(ws + xh_bytes + w1t_bytes);
    float* attn    = (float*)(ws + xh_bytes + w1t_bytes + sc_bytes);

    // Allow 128 KiB dynamic LDS (host-side attribute; not a stream op).
    hipFuncSetAttribute((const void*)gemm_fused_kernel,
                        hipFuncAttributeMaxDynamicSharedMemorySize, 131072);

    hipMemsetAsync(scores, 0, sc_bytes, stream);
    cvt_x_kernel<<<2048, 256, 0, stream>>>((const float4*)x, (half8*)xh, (Mm * Kk) / 8);
    cvt_w1_kernel<<<dim3(Dd / 32, DR / 32, Hh), 256, 0, stream>>>(W1, w1t);
    gemm_fused_kernel<<<dim3((Mm / BM) * (Nn / BN)), 512, 131072, stream>>>(xh, w1t, b1, W2, scores);
    softmax_kernel<<<Bx * Hh, Tt, 0, stream>>>(scores, attn);
    pool_kernel<<<dim3(Bx, Dd / 256), 256, 0, stream>>>(xh, attn, out);
}